// Round 16
// baseline (108.106 us; speedup 1.0000x reference)
//
#include <hip/hip_runtime.h>
#include <hip/hip_bf16.h>

using f32x4    = __attribute__((ext_vector_type(4))) float;
using f32x16   = __attribute__((ext_vector_type(16))) float;
using bf16x8   = __attribute__((ext_vector_type(8))) __bf16;
using ushort8  = __attribute__((ext_vector_type(8))) unsigned short;
using ushort4v = __attribute__((ext_vector_type(4))) unsigned short;
using uint4v   = __attribute__((ext_vector_type(4))) unsigned int;
using float4v  = __attribute__((ext_vector_type(4))) float;

#define LOG2E 1.44269504088896340736f
#define SHIFT_L2 5.77078016355585f   // 4 * log2(e): p = exp(s_true - 4)

static __device__ __forceinline__ unsigned short f2bf(float f) {
  union { __hip_bfloat16 h; unsigned short u; } cv;
  cv.h = __float2bfloat16(f);
  return cv.u;
}
static __device__ __forceinline__ bf16x8 ld_bf8_g(const void* p) {
  ushort8 u = *(const ushort8*)p;
  return __builtin_bit_cast(bf16x8, u);
}
static __device__ __forceinline__ float fast_exp2(float x) {
#if __has_builtin(__builtin_amdgcn_exp2f)
  return __builtin_amdgcn_exp2f(x);
#else
  return exp2f(x);
#endif
}
static __device__ __forceinline__ unsigned int pk2(float a, float b) {
  return (unsigned int)f2bf(a) | ((unsigned int)f2bf(b) << 16);
}

// ---- W prep: Wfrag in MFMA B-fragment order -------------------------------
// col n-tile (0..11: 0-3 q, 4-7 k, 8-11 v), k-step kk (0..31):
//   elem = (n*32+kk)*512 + (lh*16+l15)*8 + e  <- W[col=n*16+l15][k=kk*32+lh*8+e]
__global__ __launch_bounds__(256) void wprep_kernel(
    const float* __restrict__ wq, const float* __restrict__ wk,
    const float* __restrict__ wv, unsigned short* __restrict__ Wfrag) {
  int idx = blockIdx.x * 256 + threadIdx.x;   // 0 .. 196607
  int col = idx >> 10;                        // 0..191
  int k   = idx & 1023;
  const float* w = (col < 64) ? wq : (col < 128) ? wk : wv;
  int c = col & 63;
  int n = col >> 4, l15 = col & 15;
  int kk = k >> 5, lh = (k >> 3) & 3, e = k & 7;
  size_t elem = ((size_t)(n * 32 + kk) * 64 + lh * 16 + l15) * 8 + e;
  Wfrag[elem] = f2bf(w[k * 64 + c]);
}

// ---- QKV projection: barrier-free streaming GEMM, 16 waves/CU -------------
// grid 4096: wid = q*1024 + rj (q = col-quarter of 3 n-tiles, rj = 16-row
// job). Same-row quarters land on the SAME XCD (1024 % 8 == 0) -> x fetched
// into one L2. A and B double-prefetched (unroll-2 ping-pong, named regs).
__global__ __launch_bounds__(64, 4) void proj_kernel(
    const float* __restrict__ x, const unsigned short* __restrict__ Wfrag,
    const float* __restrict__ bq, const float* __restrict__ bk,
    const float* __restrict__ bv,
    unsigned short* __restrict__ qb, unsigned short* __restrict__ kreg,
    unsigned short* __restrict__ vreg) {
  int lane = threadIdx.x & 63;
  int l15 = lane & 15, lh = lane >> 4;
  int wid = blockIdx.x;
  int q = wid >> 10;                    // col quarter 0..3 (3 n-tiles)
  int rj = wid & 1023;                  // row job (16 rows)
  int rowBase = rj * 16;
  const float* xp = x + (size_t)(rowBase + l15) * 1024 + lh * 8;
  const unsigned short* wf = Wfrag + (size_t)lane * 8;

#define BFRAG(CF, KK) ld_bf8_g(wf + (((q * 3 + (CF)) * 32 + (KK)) << 9))

  f32x4 acc[3];
#pragma unroll
  for (int i = 0; i < 3; ++i) acc[i] = (f32x4){0.f, 0.f, 0.f, 0.f};

  bf16x8 bA0 = BFRAG(0, 0), bA1 = BFRAG(1, 0), bA2 = BFRAG(2, 0);
  bf16x8 bB0 = BFRAG(0, 1), bB1 = BFRAG(1, 1), bB2 = BFRAG(2, 1);
  float4v aA0 = *(const float4v*)(xp);
  float4v aA1 = *(const float4v*)(xp + 4);
  float4v aB0 = *(const float4v*)(xp + 32);
  float4v aB1 = *(const float4v*)(xp + 36);

#pragma unroll 1
  for (int kk = 0; kk < 32; kk += 2) {
    {  // even step kk: consume aA/bA, then refill for kk+2
      uint4v au = {pk2(aA0[0], aA0[1]), pk2(aA0[2], aA0[3]),
                   pk2(aA1[0], aA1[1]), pk2(aA1[2], aA1[3])};
      bf16x8 af = __builtin_bit_cast(bf16x8, au);
      acc[0] = __builtin_amdgcn_mfma_f32_16x16x32_bf16(af, bA0, acc[0], 0, 0, 0);
      acc[1] = __builtin_amdgcn_mfma_f32_16x16x32_bf16(af, bA1, acc[1], 0, 0, 0);
      acc[2] = __builtin_amdgcn_mfma_f32_16x16x32_bf16(af, bA2, acc[2], 0, 0, 0);
      if (kk + 2 < 32) {
        aA0 = *(const float4v*)(xp + (kk + 2) * 32);
        aA1 = *(const float4v*)(xp + (kk + 2) * 32 + 4);
        bA0 = BFRAG(0, kk + 2); bA1 = BFRAG(1, kk + 2); bA2 = BFRAG(2, kk + 2);
      }
    }
    {  // odd step kk+1: consume aB/bB, then refill for kk+3
      uint4v au = {pk2(aB0[0], aB0[1]), pk2(aB0[2], aB0[3]),
                   pk2(aB1[0], aB1[1]), pk2(aB1[2], aB1[3])};
      bf16x8 af = __builtin_bit_cast(bf16x8, au);
      acc[0] = __builtin_amdgcn_mfma_f32_16x16x32_bf16(af, bB0, acc[0], 0, 0, 0);
      acc[1] = __builtin_amdgcn_mfma_f32_16x16x32_bf16(af, bB1, acc[1], 0, 0, 0);
      acc[2] = __builtin_amdgcn_mfma_f32_16x16x32_bf16(af, bB2, acc[2], 0, 0, 0);
      if (kk + 3 < 32) {
        aB0 = *(const float4v*)(xp + (kk + 3) * 32);
        aB1 = *(const float4v*)(xp + (kk + 3) * 32 + 4);
        bB0 = BFRAG(0, kk + 3); bB1 = BFRAG(1, kk + 3); bB2 = BFRAG(2, kk + 3);
      }
    }
  }
#undef BFRAG

  // ---- epilogue: bias + scatter to q / K-frag / V-frag ----
#pragma unroll
  for (int cf = 0; cf < 3; ++cf) {
    int n = q * 3 + cf;
    int col = n * 16 + l15;
    int sel = col >> 6, c64 = col & 63;
    const float* bias = (sel == 0) ? bq : (sel == 1) ? bk : bv;
    float bb = bias[c64];
    if (sel == 0) {
#pragma unroll
      for (int r = 0; r < 4; ++r) {
        int row = rowBase + lh * 4 + r;
        qb[(size_t)row * 64 + c64] = f2bf((acc[cf][r] + bb) * (0.125f * LOG2E));
      }
    } else if (sel == 1) {
      int j16 = c64 >> 4, hik = (c64 >> 3) & 1, e = c64 & 7;
#pragma unroll
      for (int r = 0; r < 4; ++r) {
        int s = rowBase + lh * 4 + r;
        int b = s >> 12, sl = s & 4095;
        int ch = sl >> 7, kvw = sl & 127;
        int kvq = kvw >> 5, lk = kvw & 31;
        size_t off = (((size_t)(b * 32 + ch)) << 14) + kvq * 4096 + j16 * 1024 +
                     (hik * 32 + lk) * 16 + e * 2;
        *(unsigned short*)((char*)kreg + off) = f2bf(acc[cf][r] + bb);
      }
    } else {
      ushort4v w;
#pragma unroll
      for (int r = 0; r < 4; ++r) w[r] = f2bf(acc[cf][r] + bb);
      int s0 = rowBase + lh * 4;
      int b = s0 >> 12, sl = s0 & 4095;
      int ch = sl >> 7, kvw = sl & 127;
      int kvq = kvw >> 5, k5 = kvw & 31;
      int kj = k5 >> 4, hiv = (k5 >> 3) & 1, e0 = k5 & 7;   // e0 in {0,4}
      int dt = c64 >> 5, lv = c64 & 31, f = kj * 2 + dt;
      size_t off = (((size_t)(b * 32 + ch)) << 14) + kvq * 4096 + f * 1024 +
                   (hiv * 32 + lv) * 16 + e0 * 2;
      *(ushort4v*)((char*)vreg + off) = w;
    }
  }
}

// ---- causal flash attention v12: 8 phase-waves, paired tiles, 16 waves/CU --
// grid 512 = 2 halves x (4 batch x 64 pairs): T = ti ? p : 127-p, wid and
// wid+256 co-resident (T + T' = 127). 512 thr = 8 waves, wave = kv phase.
// Each wave streams st = ph, ph+8, ... with the fragment-order register
// pipeline (barrier-free). LDS-atomic merge of 8 phases, direct output.
__global__ __launch_bounds__(512, 4) void attn_kernel(
    const unsigned short* __restrict__ qb, const unsigned short* __restrict__ kreg,
    const unsigned short* __restrict__ vreg, float* __restrict__ out) {
  __shared__ __align__(16) float obuf[2048];   // [32 q][64 d]
  __shared__ float lsumb[32];

  int tid = threadIdx.x, wave = tid >> 6, lane = tid & 63;
  int l31 = lane & 31, hi = lane >> 5;
  int wid = blockIdx.x;
  int ti = wid >> 8;
  int j = wid & 255;
  int batch = j & 3;
  int p = j >> 2;
  int T = ti ? p : 127 - p;            // heavy+light pair per CU
  int ph = wave;                       // kv phase 0..7
  int Tq = T * 32;
  const size_t bO = (size_t)batch * 262144;
  const char* kb = (const char*)kreg + ((size_t)batch << 19);
  const char* vb = (const char*)vreg + ((size_t)batch << 19);

  // Q fragments (B-operand): lane(q=l31,hi) holds Q[Tq+q][j16*16+hi*8+e]
  const unsigned short* qp = qb + bO + (size_t)(Tq + l31) * 64 + hi * 8;
  bf16x8 qf0 = ld_bf8_g(qp);
  bf16x8 qf1 = ld_bf8_g(qp + 16);
  bf16x8 qf2 = ld_bf8_g(qp + 32);
  bf16x8 qf3 = ld_bf8_g(qp + 48);

  f32x16 o0, o1;
#pragma unroll
  for (int r = 0; r < 16; ++r) { o0[r] = 0.f; o1[r] = 0.f; }
  float lsum = 0.f;

#pragma unroll 1
  for (int st = ph; st <= T; st += 8) {
    size_t base = ((size_t)(st >> 2) << 14) + (st & 3) * 4096 + lane * 16;
    const char* kp = kb + base;
    const char* vp = vb + base;
    bf16x8 k0 = ld_bf8_g(kp);
    bf16x8 k1 = ld_bf8_g(kp + 1024);
    bf16x8 k2 = ld_bf8_g(kp + 2048);
    bf16x8 k3 = ld_bf8_g(kp + 3072);
    bf16x8 v0 = ld_bf8_g(vp);          // f=0: kj0, d-tile0
    bf16x8 v1 = ld_bf8_g(vp + 1024);   // f=1: kj0, d-tile1
    bf16x8 v2 = ld_bf8_g(vp + 2048);   // f=2: kj1, d-tile0
    bf16x8 v3 = ld_bf8_g(vp + 3072);   // f=3: kj1, d-tile1

    // ---- swapped QK^T: sc[r] = S[kv=32st+(r&3)+8(r>>2)+4hi][q=Tq+l31] ----
    f32x16 sc;
#pragma unroll
    for (int r = 0; r < 16; ++r) sc[r] = 0.f;
    sc = __builtin_amdgcn_mfma_f32_32x32x16_bf16(k0, qf0, sc, 0, 0, 0);
    sc = __builtin_amdgcn_mfma_f32_32x32x16_bf16(k1, qf1, sc, 0, 0, 0);
    sc = __builtin_amdgcn_mfma_f32_32x32x16_bf16(k2, qf2, sc, 0, 0, 0);
    sc = __builtin_amdgcn_mfma_f32_32x32x16_bf16(k3, qf3, sc, 0, 0, 0);
    if (st == T) {                     // diagonal step: causal mask
      int qg = Tq + l31;
#pragma unroll
      for (int r = 0; r < 16; ++r) {
        int kvg = 32 * st + (r & 3) + 8 * (r >> 2) + 4 * hi;
        if (kvg > qg) sc[r] = -3.0e38f;
      }
    }
    // ---- p = exp2(s - SHIFT) in-register ----
    float pv[16];
#pragma unroll
    for (int r = 0; r < 16; ++r) {
      pv[r] = fast_exp2(sc[r] - SHIFT_L2);
      lsum += pv[r];
    }
    // ---- PV: A-fragment per 16-kv slice via pack + lane^32 exchange ----
#pragma unroll
    for (int kj = 0; kj < 2; ++kj) {
      const int R = 8 * kj;
      unsigned int A0 = pk2(pv[R + 0], pv[R + 1]);
      unsigned int A1 = pk2(pv[R + 2], pv[R + 3]);
      unsigned int B0 = pk2(pv[R + 4], pv[R + 5]);
      unsigned int B1 = pk2(pv[R + 6], pv[R + 7]);
      unsigned int s0 = hi ? A0 : B0;
      unsigned int s1 = hi ? A1 : B1;
      unsigned int r0 = __shfl_xor((int)s0, 32, 64);
      unsigned int r1 = __shfl_xor((int)s1, 32, 64);
      uint4v dw = {hi ? r0 : A0, hi ? r1 : A1, hi ? B0 : r0, hi ? B1 : r1};
      bf16x8 pa = __builtin_bit_cast(bf16x8, dw);
      if (kj == 0) {
        o0 = __builtin_amdgcn_mfma_f32_32x32x16_bf16(pa, v0, o0, 0, 0, 0);
        o1 = __builtin_amdgcn_mfma_f32_32x32x16_bf16(pa, v1, o1, 0, 0, 0);
      } else {
        o0 = __builtin_amdgcn_mfma_f32_32x32x16_bf16(pa, v2, o0, 0, 0, 0);
        o1 = __builtin_amdgcn_mfma_f32_32x32x16_bf16(pa, v3, o1, 0, 0, 0);
      }
    }
  }

  // ---- lsum: combine the two hi-halves (disjoint kv sets per lane) ----
  lsum += __shfl_xor(lsum, 32, 64);

  // ---- merge 8 phase-waves via LDS atomics, normalize, store ----
  for (int i = tid; i < 2048; i += 512) obuf[i] = 0.f;
  if (tid < 32) lsumb[tid] = 0.f;
  __syncthreads();
  if (hi == 0) atomicAdd(&lsumb[l31], lsum);
#pragma unroll
  for (int r = 0; r < 16; ++r) {
    int qloc = (r & 3) + 8 * (r >> 2) + 4 * hi;
    atomicAdd(&obuf[qloc * 64 + l31], o0[r]);
    atomicAdd(&obuf[qloc * 64 + 32 + l31], o1[r]);
  }
  __syncthreads();
  {
    int row = tid >> 4, d0 = (tid & 15) * 4;
    float inv = 1.0f / lsumb[row];
    float4v vv = *(float4v*)&obuf[row * 64 + d0];
    vv *= inv;
    *(float4v*)(out + bO + (size_t)(Tq + row) * 64 + d0) = vv;
  }
}

extern "C" void kernel_launch(void* const* d_in, const int* in_sizes, int n_in,
                              void* d_out, int out_size, void* d_ws, size_t ws_size,
                              hipStream_t stream) {
  const float* x  = (const float*)d_in[0];
  const float* wq = (const float*)d_in[1];
  const float* bq = (const float*)d_in[2];
  const float* wk = (const float*)d_in[3];
  const float* bk = (const float*)d_in[4];
  const float* wv = (const float*)d_in[5];
  const float* bv = (const float*)d_in[6];

  unsigned short* Wfrag = (unsigned short*)d_ws;    // 192*1024 (B-frag order)
  unsigned short* qbuf  = Wfrag + 192 * 1024;       // [b*4096+s][64]
  unsigned short* kreg  = qbuf + 16384 * 64;        // 4 x 512 KB fragment-order
  unsigned short* vreg  = kreg + 16384 * 64;        // 4 x 512 KB fragment-order

  wprep_kernel<<<768, 256, 0, stream>>>(wq, wk, wv, Wfrag);
  proj_kernel<<<4096, 64, 0, stream>>>(x, Wfrag, bq, bk, bv, qbuf, kreg, vreg);
  attn_kernel<<<512, 512, 0, stream>>>(qbuf, kreg, vreg, (float*)d_out);
}

// Round 17
// 71.092 us; speedup vs baseline: 1.5207x; 1.5207x over previous
//
#include <hip/hip_runtime.h>
#include <hip/hip_bf16.h>

using f32x4    = __attribute__((ext_vector_type(4))) float;
using f32x16   = __attribute__((ext_vector_type(16))) float;
using bf16x8   = __attribute__((ext_vector_type(8))) __bf16;
using ushort8  = __attribute__((ext_vector_type(8))) unsigned short;
using ushort4v = __attribute__((ext_vector_type(4))) unsigned short;
using uint4v   = __attribute__((ext_vector_type(4))) unsigned int;
using float4v  = __attribute__((ext_vector_type(4))) float;

#define LOG2E 1.44269504088896340736f
#define SHIFT_L2 5.77078016355585f   // 4 * log2(e): p = exp(s_true - 4)

static __device__ __forceinline__ unsigned short f2bf(float f) {
  union { __hip_bfloat16 h; unsigned short u; } cv;
  cv.h = __float2bfloat16(f);
  return cv.u;
}
static __device__ __forceinline__ bf16x8 ld_bf8_g(const void* p) {
  ushort8 u = *(const ushort8*)p;
  return __builtin_bit_cast(bf16x8, u);
}
static __device__ __forceinline__ float fast_exp2(float x) {
#if __has_builtin(__builtin_amdgcn_exp2f)
  return __builtin_amdgcn_exp2f(x);
#else
  return exp2f(x);
#endif
}
static __device__ __forceinline__ unsigned int pk2(float a, float b) {
  return (unsigned int)f2bf(a) | ((unsigned int)f2bf(b) << 16);
}

// ---------------- W prep: Wt[col(0..191)][k(0..1023)] bf16 -------------------
__global__ __launch_bounds__(256) void wprep_kernel(
    const float* __restrict__ wq, const float* __restrict__ wk,
    const float* __restrict__ wv, unsigned short* __restrict__ Wt) {
  int idx = blockIdx.x * 256 + threadIdx.x;   // 0 .. 196607
  int col = idx >> 10;                        // 0..191
  int k   = idx & 1023;
  const float* w = (col < 64) ? wq : (col < 128) ? wk : wv;
  int c = col & 63;
  Wt[idx] = f2bf(w[k * 64 + c]);
}

// -------- QKV projection (R14 LDS-staged, measured ~25us): BM=32, BN=192 ----
// q scaled by 1/8*log2(e), layout [b*4096+s][64].
// K/V written in MFMA FRAGMENT ORDER, 16 KB per (batch, 128-kv chunk):
//  K: [ch][kvq][j16][lane][e]  <- K[kv=kvq*32+(lane&31)][col=j16*16+(lane>>5)*8+e]
//  V: [ch][kvq][f][lane][e]    <- V[kv=kvq*32+(f>>1)*16+(lane>>5)*8+e][d=(f&1)*32+(lane&31)]
__global__ __launch_bounds__(256) void proj_kernel(
    const float* __restrict__ x, const unsigned short* __restrict__ Wt,
    const float* __restrict__ bq, const float* __restrict__ bk,
    const float* __restrict__ bv,
    unsigned short* __restrict__ qb, unsigned short* __restrict__ kreg,
    unsigned short* __restrict__ vreg) {
  __shared__ __align__(16) char As[32 * 128];
  __shared__ __align__(16) char Bs[192 * 128];
  int tid = threadIdx.x, wave = tid >> 6, lane = tid & 63;
  int rowBase = blockIdx.x * 32;
  int rhalf = (wave & 1) * 16;
  int chalf = (wave >> 1) * 96;
  int l15 = lane & 15, lh = lane >> 4;

  f32x4 zero4 = {0.f, 0.f, 0.f, 0.f};
  f32x4 acc[6];
#pragma unroll
  for (int i = 0; i < 6; ++i) acc[i] = zero4;

  for (int kt = 0; kt < 16; ++kt) {
    int k0 = kt * 64;
    {
      int row = tid >> 3, c0 = (tid & 7) * 8;
      const float4v* src = (const float4v*)(x + (size_t)(rowBase + row) * 1024 + k0 + c0);
      float4v f0 = src[0], f1 = src[1];
      ushort8 u;
#pragma unroll
      for (int e = 0; e < 4; ++e) { u[e] = f2bf(f0[e]); u[4 + e] = f2bf(f1[e]); }
      *(ushort8*)(As + ((row * 128 + c0 * 2) ^ ((row & 7) << 4))) = u;
    }
#pragma unroll
    for (int i = 0; i < 6; ++i) {
      int c = tid + 256 * i;
      int col = c >> 3, kc = c & 7;
      ushort8 v = *(const ushort8*)(Wt + (size_t)col * 1024 + k0 + kc * 8);
      *(ushort8*)(Bs + ((col * 128 + kc * 16) ^ ((col & 7) << 4))) = v;
    }
    __syncthreads();
    bf16x8 a[2];
#pragma unroll
    for (int ks = 0; ks < 2; ++ks) {
      int row = rhalf + l15;
      a[ks] = ld_bf8_g(As + ((row * 128 + ks * 64 + lh * 16) ^ ((row & 7) << 4)));
    }
#pragma unroll
    for (int cf = 0; cf < 6; ++cf) {
      int col = chalf + cf * 16 + l15;
#pragma unroll
      for (int ks = 0; ks < 2; ++ks) {
        bf16x8 b = ld_bf8_g(Bs + ((col * 128 + ks * 64 + lh * 16) ^ ((col & 7) << 4)));
        acc[cf] = __builtin_amdgcn_mfma_f32_16x16x32_bf16(a[ks], b, acc[cf], 0, 0, 0);
      }
    }
    __syncthreads();
  }
#pragma unroll
  for (int cf = 0; cf < 6; ++cf) {
    int col = chalf + cf * 16 + l15;
    int sel = col >> 6, c64 = col & 63;
    const float* bias = (sel == 0) ? bq : (sel == 1) ? bk : bv;
    float bb = bias[c64];
    if (sel == 0) {
#pragma unroll
      for (int r = 0; r < 4; ++r) {
        int row = rowBase + rhalf + lh * 4 + r;
        qb[(size_t)row * 64 + c64] = f2bf((acc[cf][r] + bb) * (0.125f * LOG2E));
      }
    } else if (sel == 1) {
      int j16 = c64 >> 4, hik = (c64 >> 3) & 1, e = c64 & 7;
#pragma unroll
      for (int r = 0; r < 4; ++r) {
        int s = rowBase + rhalf + lh * 4 + r;
        int b = s >> 12, sl = s & 4095;
        int ch = sl >> 7, kvw = sl & 127;
        int kvq = kvw >> 5, lk = kvw & 31;
        size_t off = (((size_t)(b * 32 + ch)) << 14) + kvq * 4096 + j16 * 1024 +
                     (hik * 32 + lk) * 16 + e * 2;
        *(unsigned short*)((char*)kreg + off) = f2bf(acc[cf][r] + bb);
      }
    } else {
      ushort4v w;
#pragma unroll
      for (int r = 0; r < 4; ++r) w[r] = f2bf(acc[cf][r] + bb);
      int s0 = rowBase + rhalf + lh * 4;
      int b = s0 >> 12, sl = s0 & 4095;
      int ch = sl >> 7, kvw = sl & 127;
      int kvq = kvw >> 5, k5 = kvw & 31;
      int kj = k5 >> 4, hiv = (k5 >> 3) & 1, e0 = k5 & 7;   // e0 in {0,4}
      int dt = c64 >> 5, lv = c64 & 31, f = kj * 2 + dt;
      size_t off = (((size_t)(b * 32 + ch)) << 14) + kvq * 4096 + f * 1024 +
                   (hiv * 32 + lv) * 16 + e0 * 2;
      *(ushort4v*)((char*)vreg + off) = w;
    }
  }
}

// ---- causal flash attention v13: v11 + K/V register ping-pong prefetch -----
// grid 512 = 128 tiles (desc T) x 4 batch; 256 thr = 4 waves, wave = phase.
// Each wave streams st = ph, ph+4, ...: next step's K/V (8x1KB contiguous)
// prefetched into NAMED registers one step ahead (unroll-2 ping-pong).
__global__ __launch_bounds__(256, 2) void attn_kernel(
    const unsigned short* __restrict__ qb, const unsigned short* __restrict__ kreg,
    const unsigned short* __restrict__ vreg, float* __restrict__ out) {
  __shared__ __align__(16) float obuf[2048];   // [32 q][64 d]
  __shared__ float lsumb[32];

  int tid = threadIdx.x, wave = tid >> 6, lane = tid & 63;
  int l31 = lane & 31, hi = lane >> 5;
  int wid = blockIdx.x;
  int T = 127 - (wid >> 2);            // descending tile order
  int batch = wid & 3;
  int ph = wave;                       // kv phase 0..3
  int Tq = T * 32;
  const size_t bO = (size_t)batch * 262144;
  const char* kb = (const char*)kreg + ((size_t)batch << 19);
  const char* vb = (const char*)vreg + ((size_t)batch << 19);

  const unsigned short* qp = qb + bO + (size_t)(Tq + l31) * 64 + hi * 8;
  bf16x8 qf0 = ld_bf8_g(qp);
  bf16x8 qf1 = ld_bf8_g(qp + 16);
  bf16x8 qf2 = ld_bf8_g(qp + 32);
  bf16x8 qf3 = ld_bf8_g(qp + 48);

  f32x16 o0, o1;
#pragma unroll
  for (int r = 0; r < 16; ++r) { o0[r] = 0.f; o1[r] = 0.f; }
  float lsum = 0.f;

#define LOADKV(S, K0, K1, K2, K3, V0, V1, V2, V3)                          \
  {                                                                        \
    size_t base_ = ((size_t)((S) >> 2) << 14) + ((S) & 3) * 4096 + lane * 16; \
    const char* kp_ = kb + base_;                                          \
    const char* vp_ = vb + base_;                                          \
    K0 = ld_bf8_g(kp_);        K1 = ld_bf8_g(kp_ + 1024);                  \
    K2 = ld_bf8_g(kp_ + 2048); K3 = ld_bf8_g(kp_ + 3072);                  \
    V0 = ld_bf8_g(vp_);        V1 = ld_bf8_g(vp_ + 1024);                  \
    V2 = ld_bf8_g(vp_ + 2048); V3 = ld_bf8_g(vp_ + 3072);                  \
  }

#define COMPUTE(S, K0, K1, K2, K3, V0, V1, V2, V3)                         \
  {                                                                        \
    f32x16 sc;                                                             \
    _Pragma("unroll") for (int r = 0; r < 16; ++r) sc[r] = 0.f;            \
    sc = __builtin_amdgcn_mfma_f32_32x32x16_bf16(K0, qf0, sc, 0, 0, 0);    \
    sc = __builtin_amdgcn_mfma_f32_32x32x16_bf16(K1, qf1, sc, 0, 0, 0);    \
    sc = __builtin_amdgcn_mfma_f32_32x32x16_bf16(K2, qf2, sc, 0, 0, 0);    \
    sc = __builtin_amdgcn_mfma_f32_32x32x16_bf16(K3, qf3, sc, 0, 0, 0);    \
    if ((S) == T) {                                                        \
      int qg = Tq + l31;                                                   \
      _Pragma("unroll") for (int r = 0; r < 16; ++r) {                     \
        int kvg = 32 * (S) + (r & 3) + 8 * (r >> 2) + 4 * hi;              \
        if (kvg > qg) sc[r] = -3.0e38f;                                    \
      }                                                                    \
    }                                                                      \
    float pv[16];                                                          \
    _Pragma("unroll") for (int r = 0; r < 16; ++r) {                       \
      pv[r] = fast_exp2(sc[r] - SHIFT_L2);                                 \
      lsum += pv[r];                                                       \
    }                                                                      \
    _Pragma("unroll") for (int kj = 0; kj < 2; ++kj) {                     \
      const int R = 8 * kj;                                                \
      unsigned int A0 = pk2(pv[R + 0], pv[R + 1]);                         \
      unsigned int A1 = pk2(pv[R + 2], pv[R + 3]);                         \
      unsigned int B0 = pk2(pv[R + 4], pv[R + 5]);                         \
      unsigned int B1 = pk2(pv[R + 6], pv[R + 7]);                         \
      unsigned int s0 = hi ? A0 : B0;                                      \
      unsigned int s1 = hi ? A1 : B1;                                      \
      unsigned int r0 = __shfl_xor((int)s0, 32, 64);                       \
      unsigned int r1 = __shfl_xor((int)s1, 32, 64);                       \
      uint4v dw = {hi ? r0 : A0, hi ? r1 : A1, hi ? B0 : r0, hi ? B1 : r1};\
      bf16x8 pa = __builtin_bit_cast(bf16x8, dw);                          \
      if (kj == 0) {                                                       \
        o0 = __builtin_amdgcn_mfma_f32_32x32x16_bf16(pa, V0, o0, 0, 0, 0); \
        o1 = __builtin_amdgcn_mfma_f32_32x32x16_bf16(pa, V1, o1, 0, 0, 0); \
      } else {                                                             \
        o0 = __builtin_amdgcn_mfma_f32_32x32x16_bf16(pa, V2, o0, 0, 0, 0); \
        o1 = __builtin_amdgcn_mfma_f32_32x32x16_bf16(pa, V3, o1, 0, 0, 0); \
      }                                                                    \
    }                                                                      \
  }

  {
    bf16x8 kA0, kA1, kA2, kA3, vA0, vA1, vA2, vA3;
    bf16x8 kB0, kB1, kB2, kB3, vB0, vB1, vB2, vB3;
    int st = ph;
    if (st <= T) {
      LOADKV(st, kA0, kA1, kA2, kA3, vA0, vA1, vA2, vA3)
      while (true) {
        int sB = st + 4;
        if (sB <= T) LOADKV(sB, kB0, kB1, kB2, kB3, vB0, vB1, vB2, vB3)
        COMPUTE(st, kA0, kA1, kA2, kA3, vA0, vA1, vA2, vA3)
        if (sB > T) break;
        int sA = sB + 4;
        if (sA <= T) LOADKV(sA, kA0, kA1, kA2, kA3, vA0, vA1, vA2, vA3)
        COMPUTE(sB, kB0, kB1, kB2, kB3, vB0, vB1, vB2, vB3)
        if (sA > T) break;
        st = sA;
      }
    }
  }
#undef LOADKV
#undef COMPUTE

  // ---- lsum: combine the two hi-halves (disjoint kv sets per lane) ----
  lsum += __shfl_xor(lsum, 32, 64);

  // ---- merge 4 phase-waves via LDS atomics, normalize, store ----
  for (int i = tid; i < 2048; i += 256) obuf[i] = 0.f;
  if (tid < 32) lsumb[tid] = 0.f;
  __syncthreads();
  if (hi == 0) atomicAdd(&lsumb[l31], lsum);
#pragma unroll
  for (int r = 0; r < 16; ++r) {
    int qloc = (r & 3) + 8 * (r >> 2) + 4 * hi;
    atomicAdd(&obuf[qloc * 64 + l31], o0[r]);
    atomicAdd(&obuf[qloc * 64 + 32 + l31], o1[r]);
  }
  __syncthreads();
  {
    int row = tid >> 3, d0 = (tid & 7) * 8;
    float inv = 1.0f / lsumb[row];
    float4v v0 = *(float4v*)&obuf[row * 64 + d0];
    float4v v1 = *(float4v*)&obuf[row * 64 + d0 + 4];
    v0 *= inv; v1 *= inv;
    *(float4v*)(out + bO + (size_t)(Tq + row) * 64 + d0) = v0;
    *(float4v*)(out + bO + (size_t)(Tq + row) * 64 + d0 + 4) = v1;
  }
}

extern "C" void kernel_launch(void* const* d_in, const int* in_sizes, int n_in,
                              void* d_out, int out_size, void* d_ws, size_t ws_size,
                              hipStream_t stream) {
  const float* x  = (const float*)d_in[0];
  const float* wq = (const float*)d_in[1];
  const float* bq = (const float*)d_in[2];
  const float* wk = (const float*)d_in[3];
  const float* bk = (const float*)d_in[4];
  const float* wv = (const float*)d_in[5];
  const float* bv = (const float*)d_in[6];

  unsigned short* Wt   = (unsigned short*)d_ws;     // 192*1024
  unsigned short* qbuf = Wt + 192 * 1024;           // [b*4096+s][64]
  unsigned short* kreg = qbuf + 16384 * 64;         // 4 x 512 KB fragment-order
  unsigned short* vreg = kreg + 16384 * 64;         // 4 x 512 KB fragment-order

  wprep_kernel<<<768, 256, 0, stream>>>(wq, wk, wv, Wt);
  proj_kernel<<<512, 256, 0, stream>>>(x, Wt, bq, bk, bv, qbuf, kreg, vreg);
  attn_kernel<<<512, 256, 0, stream>>>(qbuf, kreg, vreg, (float*)d_out);
}

// Round 18
// 57.019 us; speedup vs baseline: 1.8960x; 1.2468x over previous
//
#include <hip/hip_runtime.h>
#include <hip/hip_bf16.h>

using f32x4    = __attribute__((ext_vector_type(4))) float;
using f32x16   = __attribute__((ext_vector_type(16))) float;
using bf16x8   = __attribute__((ext_vector_type(8))) __bf16;
using ushort8  = __attribute__((ext_vector_type(8))) unsigned short;
using ushort4v = __attribute__((ext_vector_type(4))) unsigned short;
using uint4v   = __attribute__((ext_vector_type(4))) unsigned int;
using float4v  = __attribute__((ext_vector_type(4))) float;

#define LOG2E 1.44269504088896340736f
#define SHIFT_L2 5.77078016355585f   // 4 * log2(e): p = exp(s_true - 4)

static __device__ __forceinline__ unsigned short f2bf(float f) {
  union { __hip_bfloat16 h; unsigned short u; } cv;
  cv.h = __float2bfloat16(f);
  return cv.u;
}
static __device__ __forceinline__ bf16x8 ld_bf8_g(const void* p) {
  ushort8 u = *(const ushort8*)p;
  return __builtin_bit_cast(bf16x8, u);
}
static __device__ __forceinline__ float fast_exp2(float x) {
#if __has_builtin(__builtin_amdgcn_exp2f)
  return __builtin_amdgcn_exp2f(x);
#else
  return exp2f(x);
#endif
}
static __device__ __forceinline__ unsigned int pk2(float a, float b) {
  return (unsigned int)f2bf(a) | ((unsigned int)f2bf(b) << 16);
}

// ---------------- W prep: Wt[col(0..191)][k(0..1023)] bf16 -------------------
__global__ __launch_bounds__(256) void wprep_kernel(
    const float* __restrict__ wq, const float* __restrict__ wk,
    const float* __restrict__ wv, unsigned short* __restrict__ Wt) {
  int idx = blockIdx.x * 256 + threadIdx.x;   // 0 .. 196607
  int col = idx >> 10;                        // 0..191
  int k   = idx & 1023;
  const float* w = (col < 64) ? wq : (col < 128) ? wk : wv;
  int c = col & 63;
  Wt[idx] = f2bf(w[k * 64 + c]);
}

// -------- QKV projection (R14 LDS-staged, measured ~25us): BM=32, BN=192 ----
// q scaled by 1/8*log2(e), layout [b*4096+s][64].
// K/V written in MFMA FRAGMENT ORDER, 16 KB per (batch, 128-kv chunk):
//  K: [ch][kvq][j16][lane][e]  <- K[kv=kvq*32+(lane&31)][col=j16*16+(lane>>5)*8+e]
//  V: [ch][kvq][f][lane][e]    <- V[kv=kvq*32+(f>>1)*16+(lane>>5)*8+e][d=(f&1)*32+(lane&31)]
__global__ __launch_bounds__(256) void proj_kernel(
    const float* __restrict__ x, const unsigned short* __restrict__ Wt,
    const float* __restrict__ bq, const float* __restrict__ bk,
    const float* __restrict__ bv,
    unsigned short* __restrict__ qb, unsigned short* __restrict__ kreg,
    unsigned short* __restrict__ vreg) {
  __shared__ __align__(16) char As[32 * 128];
  __shared__ __align__(16) char Bs[192 * 128];
  int tid = threadIdx.x, wave = tid >> 6, lane = tid & 63;
  int rowBase = blockIdx.x * 32;
  int rhalf = (wave & 1) * 16;
  int chalf = (wave >> 1) * 96;
  int l15 = lane & 15, lh = lane >> 4;

  f32x4 zero4 = {0.f, 0.f, 0.f, 0.f};
  f32x4 acc[6];
#pragma unroll
  for (int i = 0; i < 6; ++i) acc[i] = zero4;

  for (int kt = 0; kt < 16; ++kt) {
    int k0 = kt * 64;
    {
      int row = tid >> 3, c0 = (tid & 7) * 8;
      const float4v* src = (const float4v*)(x + (size_t)(rowBase + row) * 1024 + k0 + c0);
      float4v f0 = src[0], f1 = src[1];
      ushort8 u;
#pragma unroll
      for (int e = 0; e < 4; ++e) { u[e] = f2bf(f0[e]); u[4 + e] = f2bf(f1[e]); }
      *(ushort8*)(As + ((row * 128 + c0 * 2) ^ ((row & 7) << 4))) = u;
    }
#pragma unroll
    for (int i = 0; i < 6; ++i) {
      int c = tid + 256 * i;
      int col = c >> 3, kc = c & 7;
      ushort8 v = *(const ushort8*)(Wt + (size_t)col * 1024 + k0 + kc * 8);
      *(ushort8*)(Bs + ((col * 128 + kc * 16) ^ ((col & 7) << 4))) = v;
    }
    __syncthreads();
    bf16x8 a[2];
#pragma unroll
    for (int ks = 0; ks < 2; ++ks) {
      int row = rhalf + l15;
      a[ks] = ld_bf8_g(As + ((row * 128 + ks * 64 + lh * 16) ^ ((row & 7) << 4)));
    }
#pragma unroll
    for (int cf = 0; cf < 6; ++cf) {
      int col = chalf + cf * 16 + l15;
#pragma unroll
      for (int ks = 0; ks < 2; ++ks) {
        bf16x8 b = ld_bf8_g(Bs + ((col * 128 + ks * 64 + lh * 16) ^ ((col & 7) << 4)));
        acc[cf] = __builtin_amdgcn_mfma_f32_16x16x32_bf16(a[ks], b, acc[cf], 0, 0, 0);
      }
    }
    __syncthreads();
  }
#pragma unroll
  for (int cf = 0; cf < 6; ++cf) {
    int col = chalf + cf * 16 + l15;
    int sel = col >> 6, c64 = col & 63;
    const float* bias = (sel == 0) ? bq : (sel == 1) ? bk : bv;
    float bb = bias[c64];
    if (sel == 0) {
#pragma unroll
      for (int r = 0; r < 4; ++r) {
        int row = rowBase + rhalf + lh * 4 + r;
        qb[(size_t)row * 64 + c64] = f2bf((acc[cf][r] + bb) * (0.125f * LOG2E));
      }
    } else if (sel == 1) {
      int j16 = c64 >> 4, hik = (c64 >> 3) & 1, e = c64 & 7;
#pragma unroll
      for (int r = 0; r < 4; ++r) {
        int s = rowBase + rhalf + lh * 4 + r;
        int b = s >> 12, sl = s & 4095;
        int ch = sl >> 7, kvw = sl & 127;
        int kvq = kvw >> 5, lk = kvw & 31;
        size_t off = (((size_t)(b * 32 + ch)) << 14) + kvq * 4096 + j16 * 1024 +
                     (hik * 32 + lk) * 16 + e * 2;
        *(unsigned short*)((char*)kreg + off) = f2bf(acc[cf][r] + bb);
      }
    } else {
      ushort4v w;
#pragma unroll
      for (int r = 0; r < 4; ++r) w[r] = f2bf(acc[cf][r] + bb);
      int s0 = rowBase + rhalf + lh * 4;
      int b = s0 >> 12, sl = s0 & 4095;
      int ch = sl >> 7, kvw = sl & 127;
      int kvq = kvw >> 5, k5 = kvw & 31;
      int kj = k5 >> 4, hiv = (k5 >> 3) & 1, e0 = k5 & 7;   // e0 in {0,4}
      int dt = c64 >> 5, lv = c64 & 31, f = kj * 2 + dt;
      size_t off = (((size_t)(b * 32 + ch)) << 14) + kvq * 4096 + f * 1024 +
                   (hiv * 32 + lv) * 16 + e0 * 2;
      *(ushort4v*)((char*)vreg + off) = w;
    }
  }
}

// ---- causal flash attention v14: R14's v10 with 8 kv-phases (16 blk/CU) ----
// grid 4096 = 128 tiles (desc T) x 4 batch x 8 phases, 1-wave blocks.
// Wave streams st = ph, ph+8, ... (32 kv each): 8 contiguous 1KB loads ->
// 4 QK MFMA (swapped) -> exp -> in-reg P -> 4 PV MFMA. Partials -> po/lo.
__global__ __launch_bounds__(64, 4) void attn_kernel(
    const unsigned short* __restrict__ qb, const unsigned short* __restrict__ kreg,
    const unsigned short* __restrict__ vreg, float* __restrict__ po,
    float* __restrict__ lo) {
  int lane = threadIdx.x & 63;
  int l31 = lane & 31, hi = lane >> 5;
  int wid = blockIdx.x;
  int T = 127 - (wid >> 5);            // descending tile order (LPT)
  int low = wid & 31;
  int batch = low & 3, ph = low >> 2;  // phase 0..7
  int Tq = T * 32;
  const size_t bO = (size_t)batch * 262144;
  const char* kb = (const char*)kreg + ((size_t)batch << 19);
  const char* vb = (const char*)vreg + ((size_t)batch << 19);

  // Q fragments (B-operand): lane(q=l31,hi) holds Q[Tq+q][j16*16+hi*8+e]
  const unsigned short* qp = qb + bO + (size_t)(Tq + l31) * 64 + hi * 8;
  bf16x8 qf0 = ld_bf8_g(qp);
  bf16x8 qf1 = ld_bf8_g(qp + 16);
  bf16x8 qf2 = ld_bf8_g(qp + 32);
  bf16x8 qf3 = ld_bf8_g(qp + 48);

  f32x16 o0, o1;
#pragma unroll
  for (int r = 0; r < 16; ++r) { o0[r] = 0.f; o1[r] = 0.f; }
  float lsum = 0.f;

#pragma unroll 1
  for (int st = ph; st <= T; st += 8) {
    size_t base = ((size_t)(st >> 2) << 14) + (st & 3) * 4096 + lane * 16;
    const char* kp = kb + base;
    const char* vp = vb + base;
    bf16x8 k0 = ld_bf8_g(kp);
    bf16x8 k1 = ld_bf8_g(kp + 1024);
    bf16x8 k2 = ld_bf8_g(kp + 2048);
    bf16x8 k3 = ld_bf8_g(kp + 3072);
    bf16x8 v0 = ld_bf8_g(vp);          // f=0: kj0, d-tile0
    bf16x8 v1 = ld_bf8_g(vp + 1024);   // f=1: kj0, d-tile1
    bf16x8 v2 = ld_bf8_g(vp + 2048);   // f=2: kj1, d-tile0
    bf16x8 v3 = ld_bf8_g(vp + 3072);   // f=3: kj1, d-tile1

    // ---- swapped QK^T: sc[r] = S[kv=32st+(r&3)+8(r>>2)+4hi][q=Tq+l31] ----
    f32x16 sc;
#pragma unroll
    for (int r = 0; r < 16; ++r) sc[r] = 0.f;
    sc = __builtin_amdgcn_mfma_f32_32x32x16_bf16(k0, qf0, sc, 0, 0, 0);
    sc = __builtin_amdgcn_mfma_f32_32x32x16_bf16(k1, qf1, sc, 0, 0, 0);
    sc = __builtin_amdgcn_mfma_f32_32x32x16_bf16(k2, qf2, sc, 0, 0, 0);
    sc = __builtin_amdgcn_mfma_f32_32x32x16_bf16(k3, qf3, sc, 0, 0, 0);
    if (st == T) {                     // diagonal step: causal mask
      int qg = Tq + l31;
#pragma unroll
      for (int r = 0; r < 16; ++r) {
        int kvg = 32 * st + (r & 3) + 8 * (r >> 2) + 4 * hi;
        if (kvg > qg) sc[r] = -3.0e38f;
      }
    }
    // ---- p = exp2(s - SHIFT) in-register ----
    float pv[16];
#pragma unroll
    for (int r = 0; r < 16; ++r) {
      pv[r] = fast_exp2(sc[r] - SHIFT_L2);
      lsum += pv[r];
    }
    // ---- PV: A-fragment per 16-kv slice via pack + lane^32 exchange ----
#pragma unroll
    for (int kj = 0; kj < 2; ++kj) {
      const int R = 8 * kj;
      unsigned int A0 = pk2(pv[R + 0], pv[R + 1]);
      unsigned int A1 = pk2(pv[R + 2], pv[R + 3]);
      unsigned int B0 = pk2(pv[R + 4], pv[R + 5]);
      unsigned int B1 = pk2(pv[R + 6], pv[R + 7]);
      unsigned int s0 = hi ? A0 : B0;
      unsigned int s1 = hi ? A1 : B1;
      unsigned int r0 = __shfl_xor((int)s0, 32, 64);
      unsigned int r1 = __shfl_xor((int)s1, 32, 64);
      uint4v dw = {hi ? r0 : A0, hi ? r1 : A1, hi ? B0 : r0, hi ? B1 : r1};
      bf16x8 pa = __builtin_bit_cast(bf16x8, dw);
      if (kj == 0) {
        o0 = __builtin_amdgcn_mfma_f32_32x32x16_bf16(pa, v0, o0, 0, 0, 0);
        o1 = __builtin_amdgcn_mfma_f32_32x32x16_bf16(pa, v1, o1, 0, 0, 0);
      } else {
        o0 = __builtin_amdgcn_mfma_f32_32x32x16_bf16(pa, v2, o0, 0, 0, 0);
        o1 = __builtin_amdgcn_mfma_f32_32x32x16_bf16(pa, v3, o1, 0, 0, 0);
      }
    }
  }

  // ---- lsum: combine the two hi-halves (disjoint kv sets per lane) ----
  lsum += __shfl_xor(lsum, 32, 64);

  // ---- plain-store partial for (ph, batch, tile) ----
  float* pdst = po + (size_t)ph * 1048576 + bO + (size_t)Tq * 64;
#pragma unroll
  for (int r = 0; r < 16; ++r) {
    int qloc = (r & 3) + 8 * (r >> 2) + 4 * hi;
    pdst[qloc * 64 + l31] = o0[r];
    pdst[qloc * 64 + 32 + l31] = o1[r];
  }
  if (hi == 0) lo[ph * 16384 + batch * 4096 + Tq + l31] = lsum;
}

// ---- merge: out = sum_ph po[ph] / sum_ph lo[ph]  (8 phases) ----------------
__global__ __launch_bounds__(256) void merge_kernel(
    const float* __restrict__ po, const float* __restrict__ lo,
    float* __restrict__ out) {
  int i = blockIdx.x * 256 + threadIdx.x;    // float4 index 0..262143
  int row = i >> 4;                          // 0..16383
  float4v a = ((const float4v*)po)[i];
  float L = lo[row];
#pragma unroll
  for (int ph = 1; ph < 8; ++ph) {
    a += ((const float4v*)po)[i + ph * 262144];
    L += lo[row + ph * 16384];
  }
  a *= (1.0f / L);
  ((float4v*)out)[i] = a;
}

extern "C" void kernel_launch(void* const* d_in, const int* in_sizes, int n_in,
                              void* d_out, int out_size, void* d_ws, size_t ws_size,
                              hipStream_t stream) {
  const float* x  = (const float*)d_in[0];
  const float* wq = (const float*)d_in[1];
  const float* bq = (const float*)d_in[2];
  const float* wk = (const float*)d_in[3];
  const float* bk = (const float*)d_in[4];
  const float* wv = (const float*)d_in[5];
  const float* bv = (const float*)d_in[6];

  unsigned short* Wt   = (unsigned short*)d_ws;     // 192*1024
  unsigned short* qbuf = Wt + 192 * 1024;           // [b*4096+s][64]
  unsigned short* kreg = qbuf + 16384 * 64;         // 4 x 512 KB fragment-order
  unsigned short* vreg = kreg + 16384 * 64;         // 4 x 512 KB fragment-order
  float*          po   = (float*)(vreg + 16384 * 64);  // 8 x [4][4096][64]
  float*          lo   = po + 8 * 1048576;             // 8 x [4][4096]

  wprep_kernel<<<768, 256, 0, stream>>>(wq, wk, wv, Wt);
  proj_kernel<<<512, 256, 0, stream>>>(x, Wt, bq, bk, bv, qbuf, kreg, vreg);
  attn_kernel<<<4096, 64, 0, stream>>>(qbuf, kreg, vreg, po, lo);
  merge_kernel<<<1024, 256, 0, stream>>>(po, lo, (float*)d_out);
}

// Round 19
// 55.610 us; speedup vs baseline: 1.9440x; 1.0253x over previous
//
#include <hip/hip_runtime.h>
#include <hip/hip_bf16.h>

using f32x4    = __attribute__((ext_vector_type(4))) float;
using f32x16   = __attribute__((ext_vector_type(16))) float;
using bf16x8   = __attribute__((ext_vector_type(8))) __bf16;
using ushort8  = __attribute__((ext_vector_type(8))) unsigned short;
using ushort4v = __attribute__((ext_vector_type(4))) unsigned short;
using uint4v   = __attribute__((ext_vector_type(4))) unsigned int;
using float4v  = __attribute__((ext_vector_type(4))) float;

#define LOG2E 1.44269504088896340736f
#define SHIFT_L2 5.77078016355585f   // 4 * log2(e): p = exp(s_true - 4)

static __device__ __forceinline__ unsigned short f2bf(float f) {
  union { __hip_bfloat16 h; unsigned short u; } cv;
  cv.h = __float2bfloat16(f);
  return cv.u;
}
static __device__ __forceinline__ bf16x8 ld_bf8_g(const void* p) {
  ushort8 u = *(const ushort8*)p;
  return __builtin_bit_cast(bf16x8, u);
}
static __device__ __forceinline__ float fast_exp2(float x) {
#if __has_builtin(__builtin_amdgcn_exp2f)
  return __builtin_amdgcn_exp2f(x);
#else
  return exp2f(x);
#endif
}
static __device__ __forceinline__ unsigned int pk2(float a, float b) {
  return (unsigned int)f2bf(a) | ((unsigned int)f2bf(b) << 16);
}

// ---- W prep: Wfrag in MFMA B-fragment order (R15 layout, validated) -------
// col n-tile (0..11: 0-3 q, 4-7 k, 8-11 v), k-step kk (0..31):
//   elem = ((n*32+kk)*64 + lane)*8 + e  <- W[col=n*16+(lane&15)][k=kk*32+(lane>>4)*8+e]
__global__ __launch_bounds__(256) void wprep_kernel(
    const float* __restrict__ wq, const float* __restrict__ wk,
    const float* __restrict__ wv, unsigned short* __restrict__ Wfrag) {
  int idx = blockIdx.x * 256 + threadIdx.x;   // 0 .. 196607
  int col = idx >> 10;                        // 0..191
  int k   = idx & 1023;
  const float* w = (col < 64) ? wq : (col < 128) ? wk : wv;
  int c = col & 63;
  int n = col >> 4, l15 = col & 15;
  int kk = k >> 5, lh = (k >> 3) & 3, e = k & 7;
  size_t elem = ((size_t)(n * 32 + kk) * 64 + lh * 16 + l15) * 8 + e;
  Wfrag[elem] = f2bf(w[k * 64 + c]);
}

// ---- QKV projection v2: pipelined (B direct-from-L2 dbuf regs; A async ----
// reg->LDS dbuf; one raw s_barrier/step, no vmcnt drain). BM=32, BN=192.
// Outputs identical to R18: qb scaled, kreg/vreg fragment-order panels.
__global__ __launch_bounds__(256, 2) void proj_kernel(
    const float* __restrict__ x, const unsigned short* __restrict__ Wfrag,
    const float* __restrict__ bq, const float* __restrict__ bk,
    const float* __restrict__ bv,
    unsigned short* __restrict__ qb, unsigned short* __restrict__ kreg,
    unsigned short* __restrict__ vreg) {
  __shared__ __align__(16) char As[2][32 * 128];   // dbuf, swz (row&7)<<4
  int tid = threadIdx.x, wave = tid >> 6, lane = tid & 63;
  int rowBase = blockIdx.x * 32;
  int rhalf = (wave & 1) * 16;
  int nbase = (wave >> 1) * 6;          // 6 n-tiles of 16 cols per wave-pair
  int l15 = lane & 15, lh = lane >> 4;

  int arow = tid >> 3, ac0 = (tid & 7) * 8;   // A-stage: 8 fp32 per thread
  const float* xp = x + (size_t)(rowBase + arow) * 1024 + ac0;
  int abyte = (arow * 128 + ac0 * 2) ^ ((arow & 7) << 4);
  const char* wfb = (const char*)Wfrag + (size_t)lane * 16;

  f32x4 acc[6];
#pragma unroll
  for (int i = 0; i < 6; ++i) acc[i] = (f32x4){0.f, 0.f, 0.f, 0.f};

  float4v aL[2], aH[2];
  bf16x8 B[2][12];

  // ---- prologue: A(0)->buf0, B(0) in regs, A(1) in flight ----
  aL[0] = *(const float4v*)(xp);
  aH[0] = *(const float4v*)(xp + 4);
#pragma unroll
  for (int j = 0; j < 6; ++j) {
    B[0][j * 2]     = ld_bf8_g(wfb + (((size_t)(nbase + j) * 32 + 0) << 10));
    B[0][j * 2 + 1] = ld_bf8_g(wfb + (((size_t)(nbase + j) * 32 + 1) << 10));
  }
  {
    ushort8 u;
#pragma unroll
    for (int e = 0; e < 4; ++e) { u[e] = f2bf(aL[0][e]); u[4 + e] = f2bf(aH[0][e]); }
    *(ushort8*)(As[0] + abyte) = u;
  }
  aL[1] = *(const float4v*)(xp + 64);
  aH[1] = *(const float4v*)(xp + 68);
  asm volatile("s_waitcnt lgkmcnt(0)" ::: "memory");
  __builtin_amdgcn_s_barrier();
  __builtin_amdgcn_sched_barrier(0);

#pragma unroll
  for (int kt = 0; kt < 16; ++kt) {
    const int cur = kt & 1, nxt = cur ^ 1;
    if (kt < 15) {  // issue B(kt+1) — stays in flight through this body
#pragma unroll
      for (int j = 0; j < 6; ++j) {
        B[nxt][j * 2]     = ld_bf8_g(wfb + (((size_t)(nbase + j) * 32 + 2 * (kt + 1)) << 10));
        B[nxt][j * 2 + 1] = ld_bf8_g(wfb + (((size_t)(nbase + j) * 32 + 2 * (kt + 1) + 1) << 10));
      }
    }
    // ---- compute step kt from As[cur] + B[cur] ----
    {
      int row = rhalf + l15;
      bf16x8 a0 = ld_bf8_g(As[cur] + ((row * 128 + lh * 16) ^ ((row & 7) << 4)));
      bf16x8 a1 = ld_bf8_g(As[cur] + ((row * 128 + 64 + lh * 16) ^ ((row & 7) << 4)));
#pragma unroll
      for (int j = 0; j < 6; ++j) {
        acc[j] = __builtin_amdgcn_mfma_f32_16x16x32_bf16(a0, B[cur][j * 2], acc[j], 0, 0, 0);
        acc[j] = __builtin_amdgcn_mfma_f32_16x16x32_bf16(a1, B[cur][j * 2 + 1], acc[j], 0, 0, 0);
      }
    }
    if (kt < 15) {
      // cvt + write A(kt+1) into As[nxt]; issue A(kt+2)
      ushort8 u;
#pragma unroll
      for (int e = 0; e < 4; ++e) { u[e] = f2bf(aL[nxt][e]); u[4 + e] = f2bf(aH[nxt][e]); }
      *(ushort8*)(As[nxt] + abyte) = u;
      if (kt < 14) {
        aL[cur] = *(const float4v*)(xp + (kt + 2) * 64);
        aH[cur] = *(const float4v*)(xp + (kt + 2) * 64 + 4);
      }
      asm volatile("s_waitcnt lgkmcnt(0)" ::: "memory");
      __builtin_amdgcn_s_barrier();
      __builtin_amdgcn_sched_barrier(0);
    }
  }

  // ---- epilogue: bias + scatter to q / K-frag / V-frag (R18 verbatim) ----
#pragma unroll
  for (int cf = 0; cf < 6; ++cf) {
    int col = (nbase + cf) * 16 + l15;
    int sel = col >> 6, c64 = col & 63;
    const float* bias = (sel == 0) ? bq : (sel == 1) ? bk : bv;
    float bb = bias[c64];
    if (sel == 0) {
#pragma unroll
      for (int r = 0; r < 4; ++r) {
        int row = rowBase + rhalf + lh * 4 + r;
        qb[(size_t)row * 64 + c64] = f2bf((acc[cf][r] + bb) * (0.125f * LOG2E));
      }
    } else if (sel == 1) {
      int j16 = c64 >> 4, hik = (c64 >> 3) & 1, e = c64 & 7;
#pragma unroll
      for (int r = 0; r < 4; ++r) {
        int s = rowBase + rhalf + lh * 4 + r;
        int b = s >> 12, sl = s & 4095;
        int ch = sl >> 7, kvw = sl & 127;
        int kvq = kvw >> 5, lk = kvw & 31;
        size_t off = (((size_t)(b * 32 + ch)) << 14) + kvq * 4096 + j16 * 1024 +
                     (hik * 32 + lk) * 16 + e * 2;
        *(unsigned short*)((char*)kreg + off) = f2bf(acc[cf][r] + bb);
      }
    } else {
      ushort4v w;
#pragma unroll
      for (int r = 0; r < 4; ++r) w[r] = f2bf(acc[cf][r] + bb);
      int s0 = rowBase + rhalf + lh * 4;
      int b = s0 >> 12, sl = s0 & 4095;
      int ch = sl >> 7, kvw = sl & 127;
      int kvq = kvw >> 5, k5 = kvw & 31;
      int kj = k5 >> 4, hiv = (k5 >> 3) & 1, e0 = k5 & 7;   // e0 in {0,4}
      int dt = c64 >> 5, lv = c64 & 31, f = kj * 2 + dt;
      size_t off = (((size_t)(b * 32 + ch)) << 14) + kvq * 4096 + f * 1024 +
                   (hiv * 32 + lv) * 16 + e0 * 2;
      *(ushort4v*)((char*)vreg + off) = w;
    }
  }
}

// ---- causal flash attention v14 (R18 verbatim): 8 phases, 1-wave blocks ----
__global__ __launch_bounds__(64, 4) void attn_kernel(
    const unsigned short* __restrict__ qb, const unsigned short* __restrict__ kreg,
    const unsigned short* __restrict__ vreg, float* __restrict__ po,
    float* __restrict__ lo) {
  int lane = threadIdx.x & 63;
  int l31 = lane & 31, hi = lane >> 5;
  int wid = blockIdx.x;
  int T = 127 - (wid >> 5);            // descending tile order (LPT)
  int low = wid & 31;
  int batch = low & 3, ph = low >> 2;  // phase 0..7
  int Tq = T * 32;
  const size_t bO = (size_t)batch * 262144;
  const char* kb = (const char*)kreg + ((size_t)batch << 19);
  const char* vb = (const char*)vreg + ((size_t)batch << 19);

  const unsigned short* qp = qb + bO + (size_t)(Tq + l31) * 64 + hi * 8;
  bf16x8 qf0 = ld_bf8_g(qp);
  bf16x8 qf1 = ld_bf8_g(qp + 16);
  bf16x8 qf2 = ld_bf8_g(qp + 32);
  bf16x8 qf3 = ld_bf8_g(qp + 48);

  f32x16 o0, o1;
#pragma unroll
  for (int r = 0; r < 16; ++r) { o0[r] = 0.f; o1[r] = 0.f; }
  float lsum = 0.f;

#pragma unroll 1
  for (int st = ph; st <= T; st += 8) {
    size_t base = ((size_t)(st >> 2) << 14) + (st & 3) * 4096 + lane * 16;
    const char* kp = kb + base;
    const char* vp = vb + base;
    bf16x8 k0 = ld_bf8_g(kp);
    bf16x8 k1 = ld_bf8_g(kp + 1024);
    bf16x8 k2 = ld_bf8_g(kp + 2048);
    bf16x8 k3 = ld_bf8_g(kp + 3072);
    bf16x8 v0 = ld_bf8_g(vp);
    bf16x8 v1 = ld_bf8_g(vp + 1024);
    bf16x8 v2 = ld_bf8_g(vp + 2048);
    bf16x8 v3 = ld_bf8_g(vp + 3072);

    f32x16 sc;
#pragma unroll
    for (int r = 0; r < 16; ++r) sc[r] = 0.f;
    sc = __builtin_amdgcn_mfma_f32_32x32x16_bf16(k0, qf0, sc, 0, 0, 0);
    sc = __builtin_amdgcn_mfma_f32_32x32x16_bf16(k1, qf1, sc, 0, 0, 0);
    sc = __builtin_amdgcn_mfma_f32_32x32x16_bf16(k2, qf2, sc, 0, 0, 0);
    sc = __builtin_amdgcn_mfma_f32_32x32x16_bf16(k3, qf3, sc, 0, 0, 0);
    if (st == T) {
      int qg = Tq + l31;
#pragma unroll
      for (int r = 0; r < 16; ++r) {
        int kvg = 32 * st + (r & 3) + 8 * (r >> 2) + 4 * hi;
        if (kvg > qg) sc[r] = -3.0e38f;
      }
    }
    float pv[16];
#pragma unroll
    for (int r = 0; r < 16; ++r) {
      pv[r] = fast_exp2(sc[r] - SHIFT_L2);
      lsum += pv[r];
    }
#pragma unroll
    for (int kj = 0; kj < 2; ++kj) {
      const int R = 8 * kj;
      unsigned int A0 = pk2(pv[R + 0], pv[R + 1]);
      unsigned int A1 = pk2(pv[R + 2], pv[R + 3]);
      unsigned int B0 = pk2(pv[R + 4], pv[R + 5]);
      unsigned int B1 = pk2(pv[R + 6], pv[R + 7]);
      unsigned int s0 = hi ? A0 : B0;
      unsigned int s1 = hi ? A1 : B1;
      unsigned int r0 = __shfl_xor((int)s0, 32, 64);
      unsigned int r1 = __shfl_xor((int)s1, 32, 64);
      uint4v dw = {hi ? r0 : A0, hi ? r1 : A1, hi ? B0 : r0, hi ? B1 : r1};
      bf16x8 pa = __builtin_bit_cast(bf16x8, dw);
      if (kj == 0) {
        o0 = __builtin_amdgcn_mfma_f32_32x32x16_bf16(pa, v0, o0, 0, 0, 0);
        o1 = __builtin_amdgcn_mfma_f32_32x32x16_bf16(pa, v1, o1, 0, 0, 0);
      } else {
        o0 = __builtin_amdgcn_mfma_f32_32x32x16_bf16(pa, v2, o0, 0, 0, 0);
        o1 = __builtin_amdgcn_mfma_f32_32x32x16_bf16(pa, v3, o1, 0, 0, 0);
      }
    }
  }

  lsum += __shfl_xor(lsum, 32, 64);

  float* pdst = po + (size_t)ph * 1048576 + bO + (size_t)Tq * 64;
#pragma unroll
  for (int r = 0; r < 16; ++r) {
    int qloc = (r & 3) + 8 * (r >> 2) + 4 * hi;
    pdst[qloc * 64 + l31] = o0[r];
    pdst[qloc * 64 + 32 + l31] = o1[r];
  }
  if (hi == 0) lo[ph * 16384 + batch * 4096 + Tq + l31] = lsum;
}

// ---- merge: out = sum_ph po[ph] / sum_ph lo[ph]  (8 phases) ----------------
__global__ __launch_bounds__(256) void merge_kernel(
    const float* __restrict__ po, const float* __restrict__ lo,
    float* __restrict__ out) {
  int i = blockIdx.x * 256 + threadIdx.x;    // float4 index 0..262143
  int row = i >> 4;                          // 0..16383
  float4v a = ((const float4v*)po)[i];
  float L = lo[row];
#pragma unroll
  for (int ph = 1; ph < 8; ++ph) {
    a += ((const float4v*)po)[i + ph * 262144];
    L += lo[row + ph * 16384];
  }
  a *= (1.0f / L);
  ((float4v*)out)[i] = a;
}

extern "C" void kernel_launch(void* const* d_in, const int* in_sizes, int n_in,
                              void* d_out, int out_size, void* d_ws, size_t ws_size,
                              hipStream_t stream) {
  const float* x  = (const float*)d_in[0];
  const float* wq = (const float*)d_in[1];
  const float* bq = (const float*)d_in[2];
  const float* wk = (const float*)d_in[3];
  const float* bk = (const float*)d_in[4];
  const float* wv = (const float*)d_in[5];
  const float* bv = (const float*)d_in[6];

  unsigned short* Wfrag = (unsigned short*)d_ws;    // 192*1024 (B-frag order)
  unsigned short* qbuf  = Wfrag + 192 * 1024;       // [b*4096+s][64]
  unsigned short* kreg  = qbuf + 16384 * 64;        // 4 x 512 KB fragment-order
  unsigned short* vreg  = kreg + 16384 * 64;        // 4 x 512 KB fragment-order
  float*          po    = (float*)(vreg + 16384 * 64);  // 8 x [4][4096][64]
  float*          lo    = po + 8 * 1048576;             // 8 x [4][4096]

  wprep_kernel<<<768, 256, 0, stream>>>(wq, wk, wv, Wfrag);
  proj_kernel<<<512, 256, 0, stream>>>(x, Wfrag, bq, bk, bv, qbuf, kreg, vreg);
  attn_kernel<<<4096, 64, 0, stream>>>(qbuf, kreg, vreg, po, lo);
  merge_kernel<<<1024, 256, 0, stream>>>(po, lo, (float*)d_out);
}